// Round 13
// baseline (142.518 us; speedup 1.0000x reference)
//
#include <hip/hip_runtime.h>
#include <hip/hip_bf16.h>

// PointInstanceNorm: per-(segment, channel) normalization over [1, N, C] fp32,
// S contiguous equal segments. Structure (137.0 us at R12):
//   K1: partial sum/sumsq, DESCENDING chunk sweep (leaves x in L3 for K3),
//       ppb=1024. QUAD-stream reads this round: R12 proved stream-count (not
//       unroll depth, R9) breaks the cold-HBM read cap (2.7 -> 3.5 TB/s with
//       2 streams); 4 streams 64KB apart test the scaling.
//   K2: parallel fold (8 blocks x 256 threads, 4/channel + LDS tree) [R12].
//   K3: y = x*scale + shift, ascending; PLAIN x loads (L3-served), NT stores
//       (write stream must not evict x). FROZEN since R7.
// Ledger: K1 ~77us (3.5 TB/s), K3 ~55us, K2+overhead ~5us.

#define EPS 1e-5f

typedef float f32x4 __attribute__((ext_vector_type(4)));  // nt builtins reject HIP_vector_type

// ---------------------------------------------------------------- kernel 1
// 256 threads (4 waves), PPB=1024 contiguous points per chunk. Lane l reads
// the float4 of channels 4*(l&15)..+3 of point base+(l>>4): a wave covers
// 1KB contiguous per load. Fast path walks FOUR streams (it, it+qtr,
// it+2qtr, it+3qtr -> 64KB apart), separate accumulators -> 4 distinct DRAM
// page regions in flight. Chunk index reversed (descending sweep).
__global__ __launch_bounds__(256) void pin_stats(
    const float4* __restrict__ x4, float* __restrict__ partials,
    int ppb, long N) {
    const int tid   = threadIdx.x;
    const int lane  = tid & 63;
    const int wave  = tid >> 6;
    const int cgrp  = lane & 15;
    const int quart = lane >> 4;
    const long bchunk = (long)gridDim.x - 1 - blockIdx.x;   // descending sweep
    const long block_start = bchunk * ppb;

    float4 s = make_float4(0.f, 0.f, 0.f, 0.f);
    float4 q = make_float4(0.f, 0.f, 0.f, 0.f);

    const int iters = ppb >> 4;
    const long lane_base = (block_start + wave * 4 + quart) * 16 + cgrp;

    if (block_start + ppb <= N && (iters & 3) == 0) {
        const int qtr = iters >> 2;                  // 16 at ppb=1024
        float4 s1 = make_float4(0.f, 0.f, 0.f, 0.f), q1 = s1;
        float4 s2 = s1, q2 = s1, s3 = s1, q3 = s1;
        #pragma unroll 2
        for (int it = 0; it < qtr; ++it) {
            float4 a = x4[lane_base + (long)it * 256];
            float4 b = x4[lane_base + (long)(it + qtr) * 256];
            float4 c = x4[lane_base + (long)(it + 2 * qtr) * 256];
            float4 d = x4[lane_base + (long)(it + 3 * qtr) * 256];
            s.x  += a.x; s.y  += a.y; s.z  += a.z; s.w  += a.w;
            q.x  += a.x * a.x; q.y  += a.y * a.y; q.z  += a.z * a.z; q.w  += a.w * a.w;
            s1.x += b.x; s1.y += b.y; s1.z += b.z; s1.w += b.w;
            q1.x += b.x * b.x; q1.y += b.y * b.y; q1.z += b.z * b.z; q1.w += b.w * b.w;
            s2.x += c.x; s2.y += c.y; s2.z += c.z; s2.w += c.w;
            q2.x += c.x * c.x; q2.y += c.y * c.y; q2.z += c.z * c.z; q2.w += c.w * c.w;
            s3.x += d.x; s3.y += d.y; s3.z += d.z; s3.w += d.w;
            q3.x += d.x * d.x; q3.y += d.y * d.y; q3.z += d.z * d.z; q3.w += d.w * d.w;
        }
        s.x = (s.x + s1.x) + (s2.x + s3.x);
        s.y = (s.y + s1.y) + (s2.y + s3.y);
        s.z = (s.z + s1.z) + (s2.z + s3.z);
        s.w = (s.w + s1.w) + (s2.w + s3.w);
        q.x = (q.x + q1.x) + (q2.x + q3.x);
        q.y = (q.y + q1.y) + (q2.y + q3.y);
        q.z = (q.z + q1.z) + (q2.z + q3.z);
        q.w = (q.w + q1.w) + (q2.w + q3.w);
    } else {
        for (int it = 0; it < iters; ++it) {
            long p = block_start + (long)it * 16 + wave * 4 + quart;
            if (p < N) {
                float4 v = x4[p * 16 + cgrp];
                s.x += v.x; s.y += v.y; s.z += v.z; s.w += v.w;
                q.x += v.x * v.x; q.y += v.y * v.y; q.z += v.z * v.z; q.w += v.w * v.w;
            }
        }
    }

    #pragma unroll
    for (int off = 16; off <= 32; off <<= 1) {
        s.x += __shfl_xor(s.x, off); s.y += __shfl_xor(s.y, off);
        s.z += __shfl_xor(s.z, off); s.w += __shfl_xor(s.w, off);
        q.x += __shfl_xor(q.x, off); q.y += __shfl_xor(q.y, off);
        q.z += __shfl_xor(q.z, off); q.w += __shfl_xor(q.w, off);
    }

    __shared__ float lds[4][16][8];
    if (lane < 16) {
        lds[wave][lane][0] = s.x; lds[wave][lane][1] = s.y;
        lds[wave][lane][2] = s.z; lds[wave][lane][3] = s.w;
        lds[wave][lane][4] = q.x; lds[wave][lane][5] = q.y;
        lds[wave][lane][6] = q.z; lds[wave][lane][7] = q.w;
    }
    __syncthreads();

    if (tid < 128) {
        int stat = tid >> 6;
        int ch   = tid & 63;
        int cg   = ch >> 2;
        int j    = ch & 3;
        float v = lds[0][cg][stat * 4 + j] + lds[1][cg][stat * 4 + j]
                + lds[2][cg][stat * 4 + j] + lds[3][cg][stat * 4 + j];
        partials[bchunk * 128 + tid] = v;
    }
}

// ---------------------------------------------------------------- kernel 2
// One block per segment, 256 threads: 4 threads per channel fold interleaved
// chunk subsets, then a fixed-order LDS tree combines the 4 sub-partials.
__global__ __launch_bounds__(256) void pin_scale(
    const float* __restrict__ partials,
    const float* __restrict__ weight, const float* __restrict__ bias,
    const int* __restrict__ offs,
    float* __restrict__ scale, float* __restrict__ shift, int ppb) {
    const int s = blockIdx.x;
    const int c = threadIdx.x & 63;
    const int r = threadIdx.x >> 6;          // 0..3
    const int b0 = offs[s] / ppb;
    const int b1 = offs[s + 1] / ppb;

    float sum = 0.f, sq = 0.f;
    for (int blk = b0 + r; blk < b1; blk += 4) {
        sum += partials[(long)blk * 128 + c];
        sq  += partials[(long)blk * 128 + 64 + c];
    }

    __shared__ float lsum[4][64];
    __shared__ float lsq[4][64];
    lsum[r][c] = sum;
    lsq[r][c]  = sq;
    __syncthreads();

    if (r == 0) {
        float tsum = ((lsum[0][c] + lsum[1][c]) + lsum[2][c]) + lsum[3][c];
        float tsq  = ((lsq[0][c]  + lsq[1][c])  + lsq[2][c])  + lsq[3][c];
        float cnt  = (float)(offs[s + 1] - offs[s]);
        float mean = tsum / cnt;
        float var  = tsq / cnt - mean * mean;
        float sc   = weight[c] * rsqrtf(var + EPS);
        scale[s * 64 + c] = sc;
        shift[s * 64 + c] = bias[c] - mean * sc;
    }
}

// ---------------------------------------------------------------- kernel 3
// y = x*scale + shift, float4 in / nt-float4 out, ascending streaming.
// Identical to R7/R9 (proven): 4096 blocks x 256 threads x 16 float4.
#define K3_THREADS 256
#define K3_ITERS 16
__global__ __launch_bounds__(K3_THREADS) void pin_norm(
    const f32x4* __restrict__ x4, const int* __restrict__ bidx,
    const float4* __restrict__ scale4, const float4* __restrict__ shift4,
    f32x4* __restrict__ y4, long total4) {
    const long chunk = (long)blockIdx.x * (K3_THREADS * K3_ITERS);
    const int  tid   = threadIdx.x;
    const long p0    = chunk >> 4;
    const int  seg   = bidx[p0];
    const int  cgrp  = tid & 15;

    const float4 sc = scale4[seg * 16 + cgrp];
    const float4 sh = shift4[seg * 16 + cgrp];

    if (chunk + K3_THREADS * K3_ITERS <= total4) {
        #pragma unroll
        for (int k = 0; k < K3_ITERS; ++k) {
            long i = chunk + (long)k * K3_THREADS + tid;
            f32x4 v = x4[i];
            f32x4 o;
            o.x = v.x * sc.x + sh.x;
            o.y = v.y * sc.y + sh.y;
            o.z = v.z * sc.z + sh.z;
            o.w = v.w * sc.w + sh.w;
            __builtin_nontemporal_store(o, &y4[i]);
        }
    } else {
        for (int k = 0; k < K3_ITERS; ++k) {
            long i = chunk + (long)k * K3_THREADS + tid;
            if (i < total4) {
                f32x4 v = x4[i];
                f32x4 o;
                o.x = v.x * sc.x + sh.x;
                o.y = v.y * sc.y + sh.y;
                o.z = v.z * sc.z + sh.z;
                o.w = v.w * sc.w + sh.w;
                __builtin_nontemporal_store(o, &y4[i]);
            }
        }
    }
}

// ---------------------------------------------------------------- launcher
extern "C" void kernel_launch(void* const* d_in, const int* in_sizes, int n_in,
                              void* d_out, int out_size, void* d_ws, size_t ws_size,
                              hipStream_t stream) {
    const float* x       = (const float*)d_in[0];
    const float* weight  = (const float*)d_in[1];
    const float* bias    = (const float*)d_in[2];
    const int*   offs    = (const int*)d_in[3];
    const int*   bidx    = (const int*)d_in[4];
    float* out = (float*)d_out;

    const long C = in_sizes[1];          // 64
    const long N = (long)in_sizes[0] / C;
    const int  S = in_sizes[3] - 1;      // number of segments

    // ppb=1024 (proven; 1024 chunks @ N=1M)
    int ppb = 1024;
    long nb1;
    for (;;) {
        nb1 = (N + ppb - 1) / ppb;
        size_t need = (size_t)(nb1 * 128 + 2 * S * 64) * sizeof(float);
        if (need <= ws_size || ppb >= (1 << 20)) break;
        ppb <<= 1;
    }

    float* partials = (float*)d_ws;
    float* scale    = partials + nb1 * 128;
    float* shift    = scale + S * 64;

    pin_stats<<<(int)nb1, 256, 0, stream>>>((const float4*)x, partials, ppb, N);
    pin_scale<<<S, 256, 0, stream>>>(partials, weight, bias, offs, scale, shift, ppb);

    const long total4 = N * (C / 4);
    const long nb3 = (total4 + (K3_THREADS * K3_ITERS) - 1) / (K3_THREADS * K3_ITERS);
    pin_norm<<<(int)nb3, K3_THREADS, 0, stream>>>(
        (const f32x4*)x, bidx, (const float4*)scale, (const float4*)shift,
        (f32x4*)out, total4);
}

// Round 14
// 137.272 us; speedup vs baseline: 1.0382x; 1.0382x over previous
//
#include <hip/hip_runtime.h>
#include <hip/hip_bf16.h>

// PointInstanceNorm: per-(segment, channel) normalization over [1, N, C] fp32,
// S contiguous equal segments. Best so far 137.0 us (R12). Ledger:
//   K1 ~77us (268MB cold-HBM read @ 3.5 TB/s), K2+ovh ~5us, K3 ~55us.
// This round, ONE variable -- K1's device-level access pattern:
//   OLD: each block owns a contiguous 256KB chunk (device = ~8K scattered
//        1KB hot spots; DRAM row churn; reads cap at 2.7-3.5 TB/s).
//   NEW: grid-stride sweep WITHIN each segment (128 blocks interleave 4KB
//        pieces; device reads one contiguous sliding window per segment) --
//        the pattern of the 6.3-6.9 TB/s copy/fill benchmarks.
// K2: parallel fold (4 threads/channel + LDS tree), now over bps per-block
//     partials per segment. K3 FROZEN since R7: plain x loads (all of x is
//     L3-resident after K1 -- x exactly fits, K1 touches each line once),
//     NON-TEMPORAL y stores (write stream must not evict x).

#define EPS 1e-5f

typedef float f32x4 __attribute__((ext_vector_type(4)));  // nt builtins reject HIP_vector_type

// ---------------------------------------------------------------- kernel 1
// bps blocks per segment, 256 threads (4 waves). Block-iteration = 16 points
// = 4KB contiguous (wave w covers points 4w..4w+3; lane l reads float4 of
// channels 4*(l&15).. of point 4w+(l>>4)). Block sub reads pieces
// it*bps+sub, it ascending: all bps blocks form one sliding window.
// Partials indexed by global blockIdx (seg*bps+sub).
__global__ __launch_bounds__(256) void pin_stats(
    const float4* __restrict__ x4, float* __restrict__ partials,
    const int* __restrict__ offs, int bps, long N) {
    const int tid   = threadIdx.x;
    const int lane  = tid & 63;
    const int wave  = tid >> 6;
    const int cgrp  = lane & 15;
    const int quart = lane >> 4;
    const int bid   = blockIdx.x;
    const int seg   = bid / bps;
    const int sub   = bid - seg * bps;
    const long seg_start = offs[seg];
    const long seg_len   = (long)offs[seg + 1] - seg_start;

    float4 s = make_float4(0.f, 0.f, 0.f, 0.f);
    float4 q = make_float4(0.f, 0.f, 0.f, 0.f);

    if (seg_len % ((long)bps * 16) == 0) {
        // fast path: equal tiling, no bounds checks
        const long my_iters = seg_len / ((long)bps * 16);
        const long step4    = (long)bps * 256;     // float4 stride per iter
        long addr = (seg_start + (long)sub * 16 + wave * 4 + quart) * 16 + cgrp;
        #pragma unroll 8
        for (long it = 0; it < my_iters; ++it) {
            float4 v = x4[addr + it * step4];
            s.x += v.x; s.y += v.y; s.z += v.z; s.w += v.w;
            q.x += v.x * v.x; q.y += v.y * v.y; q.z += v.z * v.z; q.w += v.w * v.w;
        }
    } else {
        // generic path: per-point guard
        const long iters_total = (seg_len + 15) >> 4;
        for (long it = sub; it < iters_total; it += bps) {
            long p = seg_start + it * 16 + wave * 4 + quart;
            if (p < seg_start + seg_len && p < N) {
                float4 v = x4[p * 16 + cgrp];
                s.x += v.x; s.y += v.y; s.z += v.z; s.w += v.w;
                q.x += v.x * v.x; q.y += v.y * v.y; q.z += v.z * v.z; q.w += v.w * v.w;
            }
        }
    }

    #pragma unroll
    for (int off = 16; off <= 32; off <<= 1) {
        s.x += __shfl_xor(s.x, off); s.y += __shfl_xor(s.y, off);
        s.z += __shfl_xor(s.z, off); s.w += __shfl_xor(s.w, off);
        q.x += __shfl_xor(q.x, off); q.y += __shfl_xor(q.y, off);
        q.z += __shfl_xor(q.z, off); q.w += __shfl_xor(q.w, off);
    }

    __shared__ float lds[4][16][8];
    if (lane < 16) {
        lds[wave][lane][0] = s.x; lds[wave][lane][1] = s.y;
        lds[wave][lane][2] = s.z; lds[wave][lane][3] = s.w;
        lds[wave][lane][4] = q.x; lds[wave][lane][5] = q.y;
        lds[wave][lane][6] = q.z; lds[wave][lane][7] = q.w;
    }
    __syncthreads();

    if (tid < 128) {
        int stat = tid >> 6;
        int ch   = tid & 63;
        int cg   = ch >> 2;
        int j    = ch & 3;
        float v = lds[0][cg][stat * 4 + j] + lds[1][cg][stat * 4 + j]
                + lds[2][cg][stat * 4 + j] + lds[3][cg][stat * 4 + j];
        partials[(long)bid * 128 + tid] = v;
    }
}

// ---------------------------------------------------------------- kernel 2
// One block per segment, 256 threads: 4 threads per channel fold interleaved
// per-block partials (blocks seg*bps .. seg*bps+bps-1), fixed-order LDS tree.
__global__ __launch_bounds__(256) void pin_scale(
    const float* __restrict__ partials,
    const float* __restrict__ weight, const float* __restrict__ bias,
    const int* __restrict__ offs,
    float* __restrict__ scale, float* __restrict__ shift, int bps) {
    const int s = blockIdx.x;
    const int c = threadIdx.x & 63;
    const int r = threadIdx.x >> 6;          // 0..3
    const int b0 = s * bps;
    const int b1 = b0 + bps;

    float sum = 0.f, sq = 0.f;
    for (int blk = b0 + r; blk < b1; blk += 4) {
        sum += partials[(long)blk * 128 + c];
        sq  += partials[(long)blk * 128 + 64 + c];
    }

    __shared__ float lsum[4][64];
    __shared__ float lsq[4][64];
    lsum[r][c] = sum;
    lsq[r][c]  = sq;
    __syncthreads();

    if (r == 0) {
        float tsum = ((lsum[0][c] + lsum[1][c]) + lsum[2][c]) + lsum[3][c];
        float tsq  = ((lsq[0][c]  + lsq[1][c])  + lsq[2][c])  + lsq[3][c];
        float cnt  = (float)(offs[s + 1] - offs[s]);
        float mean = tsum / cnt;
        float var  = tsq / cnt - mean * mean;
        float sc   = weight[c] * rsqrtf(var + EPS);
        scale[s * 64 + c] = sc;
        shift[s * 64 + c] = bias[c] - mean * sc;
    }
}

// ---------------------------------------------------------------- kernel 3
// y = x*scale + shift, float4 in / nt-float4 out, ascending streaming.
// Identical to R7/R9/R12 (proven): 4096 blocks x 256 threads x 16 float4.
#define K3_THREADS 256
#define K3_ITERS 16
__global__ __launch_bounds__(K3_THREADS) void pin_norm(
    const f32x4* __restrict__ x4, const int* __restrict__ bidx,
    const float4* __restrict__ scale4, const float4* __restrict__ shift4,
    f32x4* __restrict__ y4, long total4) {
    const long chunk = (long)blockIdx.x * (K3_THREADS * K3_ITERS);
    const int  tid   = threadIdx.x;
    const long p0    = chunk >> 4;
    const int  seg   = bidx[p0];
    const int  cgrp  = tid & 15;

    const float4 sc = scale4[seg * 16 + cgrp];
    const float4 sh = shift4[seg * 16 + cgrp];

    if (chunk + K3_THREADS * K3_ITERS <= total4) {
        #pragma unroll
        for (int k = 0; k < K3_ITERS; ++k) {
            long i = chunk + (long)k * K3_THREADS + tid;
            f32x4 v = x4[i];
            f32x4 o;
            o.x = v.x * sc.x + sh.x;
            o.y = v.y * sc.y + sh.y;
            o.z = v.z * sc.z + sh.z;
            o.w = v.w * sc.w + sh.w;
            __builtin_nontemporal_store(o, &y4[i]);
        }
    } else {
        for (int k = 0; k < K3_ITERS; ++k) {
            long i = chunk + (long)k * K3_THREADS + tid;
            if (i < total4) {
                f32x4 v = x4[i];
                f32x4 o;
                o.x = v.x * sc.x + sh.x;
                o.y = v.y * sc.y + sh.y;
                o.z = v.z * sc.z + sh.z;
                o.w = v.w * sc.w + sh.w;
                __builtin_nontemporal_store(o, &y4[i]);
            }
        }
    }
}

// ---------------------------------------------------------------- launcher
extern "C" void kernel_launch(void* const* d_in, const int* in_sizes, int n_in,
                              void* d_out, int out_size, void* d_ws, size_t ws_size,
                              hipStream_t stream) {
    const float* x       = (const float*)d_in[0];
    const float* weight  = (const float*)d_in[1];
    const float* bias    = (const float*)d_in[2];
    const int*   offs    = (const int*)d_in[3];
    const int*   bidx    = (const int*)d_in[4];
    float* out = (float*)d_out;

    const long C = in_sizes[1];          // 64
    const long N = (long)in_sizes[0] / C;
    const int  S = in_sizes[3] - 1;      // number of segments

    // 128 blocks per segment -> grid 1024 @ S=8 (same grid/occupancy as R12)
    int bps = 128;
    while ((size_t)((long)S * bps * 128 + 2 * S * 64) * sizeof(float) > ws_size
           && bps > 8)
        bps >>= 1;

    float* partials = (float*)d_ws;
    float* scale    = partials + (long)S * bps * 128;
    float* shift    = scale + S * 64;

    pin_stats<<<S * bps, 256, 0, stream>>>((const float4*)x, partials, offs, bps, N);
    pin_scale<<<S, 256, 0, stream>>>(partials, weight, bias, offs, scale, shift, bps);

    const long total4 = N * (C / 4);
    const long nb3 = (total4 + (K3_THREADS * K3_ITERS) - 1) / (K3_THREADS * K3_ITERS);
    pin_norm<<<(int)nb3, K3_THREADS, 0, stream>>>(
        (const f32x4*)x, bidx, (const float4*)scale, (const float4*)shift,
        (f32x4*)out, total4);
}